// Round 11
// baseline (1128.910 us; speedup 1.0000x reference)
//
#include <hip/hip_runtime.h>
#include <math.h>

// MicroEncoder: 4-layer bidirectional Mamba2.
// B=8, L=2048, D_MODEL=256, D_INNER=512, NHEADS=8, HEADDIM=64, D_STATE=64,
// CONV_DIM=640, D_IN_PROJ=1160.
// Round 11: conv output stored as split-bf16 hi/lo PLANES (same bytes as the
// old fp32 xc). The fp32->hi/lo conversion happens ONCE in k_conv (which has
// idle VALU); k_scan1 / k_scan3f staging becomes pure 16B copies. scan1-P3
// reads x as hi+lo from LDS and writes ylocal split hi/lo back to the planes;
// scan3f reconstructs ylocal as hi+lo.

#define TC 64
#define NC 32
#define SPITCH 72
#define HIOFF 8388608    // ushort offset of lo plane within one dir's hinp

// per-dir strides
#define ZB_STR   8388608u    // ushorts (16384x512)
#define XBCB_STR 10485760u   // ushorts (16384x640)
#define HINP_STR 16777216u   // ushorts (hi+lo planes)
#define XCV_STR  20971520u   // ushorts (xc hi+lo planes per dir)
#define XCLO     10485760u   // ushort offset of xc lo plane within dir
#define DT_STR   131072u     // floats
#define SB_STR   131072u     // floats
#define PT_STR   2048u       // floats

typedef __attribute__((ext_vector_type(4))) float f32x4;
typedef __attribute__((ext_vector_type(8))) short s16x8;

#define MFMA __builtin_amdgcn_mfma_f32_16x16x32_bf16

__device__ __forceinline__ float siluf(float x) { return x / (1.f + expf(-x)); }

__device__ __forceinline__ ushort f2b(float f) {
  union { float f; uint u; } v; v.f = f;
  return (ushort)((v.u + 0x7FFFu + ((v.u >> 16) & 1u)) >> 16);
}
__device__ __forceinline__ float b2f(ushort u) {
  union { uint u; float f; } v; v.u = ((uint)u) << 16; return v.f;
}
__device__ __forceinline__ int swz(int r, int c) { return c ^ (r & 3) ^ ((r >> 2) & 3); }

__device__ __forceinline__ int soff(int base, int r, int cc) {
  return base + r * SPITCH + ((((cc >> 3) ^ (r & 7) ^ ((r >> 3) & 7)) << 3) | (cc & 7));
}
__device__ __forceinline__ int toff(int base, int r, int cc) {
  return base + r * 64 + ((((cc >> 3) ^ (r & 7)) << 3) | (cc & 7));
}

__global__ __launch_bounds__(256) void k_cvt(
    const float* __restrict__ src, ushort* __restrict__ dst, int n8)
{
  const int i = blockIdx.x * 256 + threadIdx.x;
  if (i >= n8) return;
  const float4 v0 = *(const float4*)(src + (size_t)i * 8);
  const float4 v1 = *(const float4*)(src + (size_t)i * 8 + 4);
  s16x8 h;
#pragma unroll
  for (int e = 0; e < 4; ++e) h[e] = (short)f2b(((const float*)&v0)[e]);
#pragma unroll
  for (int e = 0; e < 4; ++e) h[e + 4] = (short)f2b(((const float*)&v1)[e]);
  *(s16x8*)(dst + (size_t)i * 8) = h;
}

// ---------------------------------------------------------------------------
// in_proj GEMM, direction-batched via blockIdx.z. (unchanged from round 10)
// ---------------------------------------------------------------------------
__global__ __launch_bounds__(256) void k_gemmb(
    const ushort* __restrict__ A, const ushort* __restrict__ Winb, int layer,
    ushort* __restrict__ zb, ushort* __restrict__ xbc,
    const float* __restrict__ db0, const float* __restrict__ db1,
    const float* __restrict__ Al0, const float* __restrict__ Al1,
    float* __restrict__ dtb, float* __restrict__ dab)
{
  const int zd = blockIdx.z;
  const ushort* W = Winb + ((size_t)zd * 4 + layer) * 296960;  // 1160*256
  zb  += (size_t)zd * ZB_STR;
  xbc += (size_t)zd * XBCB_STR;
  dtb += (size_t)zd * DT_STR;
  dab += (size_t)zd * DT_STR;
  const float* dt_bias = zd ? db1 : db0;
  const float* A_log   = zd ? Al1 : Al0;
  const int N = 1160, K = 256;

  __shared__ __align__(16) ushort lds[17408];
  const int tid = threadIdx.x;
  const int lane = tid & 63;
  const int wid = tid >> 6;
  const int wr = wid >> 1, wc = wid & 1;
  const int m0 = blockIdx.x * 128, n0 = blockIdx.y * 128;

  const int tr = tid >> 1;
  const int th = tid & 1;
  const int gm = m0 + tr;
  const int bb = gm >> 11, tt = gm & 2047;
  const int tphys = zd ? (2047 - tt) : tt;
  const ushort* Arow = A + (size_t)((bb << 11) + tphys) * 256 + th * 16;
  const int wn = n0 + tr;
  const ushort* Wrow = (wn < N) ? (W + (size_t)wn * K + th * 16) : nullptr;

  const int asw0 = tr * 32 + swz(tr, th * 2) * 8;
  const int asw1 = tr * 32 + swz(tr, th * 2 + 1) * 8;

  f32x4 acc[4][4];
#pragma unroll
  for (int i = 0; i < 4; ++i)
#pragma unroll
    for (int j = 0; j < 4; ++j) acc[i][j] = (f32x4){0.f, 0.f, 0.f, 0.f};

  int aoff[4], boff[4];
#pragma unroll
  for (int f = 0; f < 4; ++f) {
    const int ar = wr * 64 + f * 16 + (lane & 15);
    aoff[f] = ar * 32 + swz(ar, lane >> 4) * 8;
    const int br = wc * 64 + f * 16 + (lane & 15);
    boff[f] = 4096 + br * 32 + swz(br, lane >> 4) * 8;
  }

  const s16x8 zz = (s16x8){0, 0, 0, 0, 0, 0, 0, 0};
  s16x8 a0 = *(const s16x8*)(Arow);
  s16x8 a1 = *(const s16x8*)(Arow + 8);
  s16x8 b0 = zz, b1 = zz;
  if (Wrow) {
    b0 = *(const s16x8*)(Wrow);
    b1 = *(const s16x8*)(Wrow + 8);
  }

  for (int k0 = 0; k0 < K; k0 += 32) {
    __syncthreads();
    *(s16x8*)&lds[asw0] = a0;
    *(s16x8*)&lds[asw1] = a1;
    *(s16x8*)&lds[4096 + asw0] = b0;
    *(s16x8*)&lds[4096 + asw1] = b1;
    __syncthreads();
    if (k0 + 32 < K) {
      a0 = *(const s16x8*)(Arow + k0 + 32);
      a1 = *(const s16x8*)(Arow + k0 + 40);
      if (Wrow) {
        b0 = *(const s16x8*)(Wrow + k0 + 32);
        b1 = *(const s16x8*)(Wrow + k0 + 40);
      }
    }
    s16x8 af[4], bf[4];
#pragma unroll
    for (int f = 0; f < 4; ++f) {
      af[f] = *(const s16x8*)&lds[aoff[f]];
      bf[f] = *(const s16x8*)&lds[boff[f]];
    }
#pragma unroll
    for (int i = 0; i < 4; ++i)
#pragma unroll
      for (int j = 0; j < 4; ++j)
        acc[i][j] = MFMA(af[i], bf[j], acc[i][j], 0, 0, 0);
  }

  const int by = blockIdx.y;
  if (by == 9) {
    if (wc == 0 && (lane & 15) < 8) {
      const int cl = lane & 15;
      const float bias = dt_bias[cl];
      const float eAl = expf(A_log[cl]);
#pragma unroll
      for (int i = 0; i < 4; ++i) {
        const int r = m0 + wr * 64 + i * 16 + (lane >> 4) * 4;
#pragma unroll
        for (int g = 0; g < 4; ++g) {
          const float v = acc[i][0][g] + bias;
          const float sp = (v > 20.f) ? v : log1pf(expf(v));
          dtb[(size_t)(r + g) * 8 + cl] = sp;
          dab[(size_t)(r + g) * 8 + cl] = sp * eAl;
        }
      }
    }
    return;
  }
  __syncthreads();
#pragma unroll
  for (int i = 0; i < 4; ++i) {
    const int r = wr * 64 + i * 16 + (lane >> 4) * 4;
#pragma unroll
    for (int j = 0; j < 4; ++j) {
      const int ccol = wc * 64 + j * 16 + (lane & 15);
#pragma unroll
      for (int g = 0; g < 4; ++g)
        lds[(r + g) * 136 + ccol] = f2b(acc[i][j][g]);
    }
  }
  __syncthreads();
  const int rr = tid >> 1, hf = tid & 1;
  const int grow = m0 + rr;
  ushort* dst; int stride, colb;
  if (by < 4) { dst = zb;  stride = 512; colb = n0; }
  else        { dst = xbc; stride = 640; colb = n0 - 512; }
  ushort* dp = dst + (size_t)grow * stride + colb + hf * 64;
  const ushort* sp = &lds[rr * 136 + hf * 64];
#pragma unroll
  for (int q = 0; q < 8; ++q)
    *(s16x8*)(dp + q * 8) = *(const s16x8*)(sp + q * 8);
}

// ---------------------------------------------------------------------------
// Fused out_proj for layers 0-2 (unchanged from round 10).
// ---------------------------------------------------------------------------
__global__ __launch_bounds__(256) void k_gemmo_mid(
    const ushort* __restrict__ ybf, const ushort* __restrict__ Woutb, int layer,
    ushort* __restrict__ xbf)
{
  __shared__ __align__(16) ushort lds[8192];
  const int tid = threadIdx.x;
  const int lane = tid & 63;
  const int wid = tid >> 6;
  const int wr = wid >> 1, wc = wid & 1;
  const int m0 = blockIdx.x * 128, n0 = blockIdx.y * 128;

  const int tr = tid >> 1;
  const int th = tid & 1;
  const int gm = m0 + tr;
  const int bb = gm >> 11, tt = gm & 2047;
  const int wn = n0 + tr;

  const int asw0 = tr * 32 + swz(tr, th * 2) * 8;
  const int asw1 = tr * 32 + swz(tr, th * 2 + 1) * 8;

  f32x4 acc[4][4];
#pragma unroll
  for (int i = 0; i < 4; ++i)
#pragma unroll
    for (int j = 0; j < 4; ++j) acc[i][j] = (f32x4){0.f, 0.f, 0.f, 0.f};

  int aoff[4], boff[4];
#pragma unroll
  for (int f = 0; f < 4; ++f) {
    const int ar = wr * 64 + f * 16 + (lane & 15);
    aoff[f] = ar * 32 + swz(ar, lane >> 4) * 8;
    const int br = wc * 64 + f * 16 + (lane & 15);
    boff[f] = 4096 + br * 32 + swz(br, lane >> 4) * 8;
  }

  for (int dir = 0; dir < 2; ++dir) {
    const int tphys = dir ? (2047 - tt) : tt;
    const ushort* Arow = ybf + (size_t)dir * ZB_STR
                       + (size_t)((bb << 11) + tphys) * 512 + th * 16;
    const ushort* Wrow = Woutb + ((size_t)dir * 4 + layer) * 131072
                       + (size_t)wn * 512 + th * 16;
    s16x8 a0 = *(const s16x8*)(Arow);
    s16x8 a1 = *(const s16x8*)(Arow + 8);
    s16x8 b0 = *(const s16x8*)(Wrow);
    s16x8 b1 = *(const s16x8*)(Wrow + 8);
    for (int k0 = 0; k0 < 512; k0 += 32) {
      __syncthreads();
      *(s16x8*)&lds[asw0] = a0;
      *(s16x8*)&lds[asw1] = a1;
      *(s16x8*)&lds[4096 + asw0] = b0;
      *(s16x8*)&lds[4096 + asw1] = b1;
      __syncthreads();
      if (k0 + 32 < 512) {
        a0 = *(const s16x8*)(Arow + k0 + 32);
        a1 = *(const s16x8*)(Arow + k0 + 40);
        b0 = *(const s16x8*)(Wrow + k0 + 32);
        b1 = *(const s16x8*)(Wrow + k0 + 40);
      }
      s16x8 af[4], bf[4];
#pragma unroll
      for (int f = 0; f < 4; ++f) {
        af[f] = *(const s16x8*)&lds[aoff[f]];
        bf[f] = *(const s16x8*)&lds[boff[f]];
      }
#pragma unroll
      for (int i = 0; i < 4; ++i)
#pragma unroll
        for (int j = 0; j < 4; ++j)
          acc[i][j] = MFMA(af[i], bf[j], acc[i][j], 0, 0, 0);
    }
  }

#pragma unroll
  for (int i = 0; i < 4; ++i) {
    const int rb = m0 + wr * 64 + i * 16 + (lane >> 4) * 4;
#pragma unroll
    for (int g = 0; g < 4; ++g) {
      const size_t rbase = (size_t)(rb + g) * 256 + n0 + wc * 64 + (lane & 15);
#pragma unroll
      for (int j = 0; j < 4; ++j)
        xbf[rbase + j * 16] = f2b(acc[i][j][g]);
    }
  }
}

// ---------------------------------------------------------------------------
// Last-layer out_proj (unchanged from round 10).
// ---------------------------------------------------------------------------
__global__ __launch_bounds__(256) void k_gemmo_last(
    const ushort* __restrict__ ybf, const ushort* __restrict__ Woutb,
    float* __restrict__ hF, float* __restrict__ hB)
{
  const int zd = blockIdx.z;
  const ushort* A = ybf + (size_t)zd * ZB_STR;
  const ushort* W = Woutb + ((size_t)zd * 4 + 3) * 131072;
  float* Cout = zd ? hB : hF;

  __shared__ __align__(16) ushort lds[8192];
  const int tid = threadIdx.x;
  const int lane = tid & 63;
  const int wid = tid >> 6;
  const int wr = wid >> 1, wc = wid & 1;
  const int m0 = blockIdx.x * 128, n0 = blockIdx.y * 128;

  const int tr = tid >> 1;
  const int th = tid & 1;
  const int gm = m0 + tr;
  const ushort* Arow = A + (size_t)gm * 512 + th * 16;
  const int wn = n0 + tr;
  const ushort* Wrow = W + (size_t)wn * 512 + th * 16;

  const int asw0 = tr * 32 + swz(tr, th * 2) * 8;
  const int asw1 = tr * 32 + swz(tr, th * 2 + 1) * 8;

  f32x4 acc[4][4];
#pragma unroll
  for (int i = 0; i < 4; ++i)
#pragma unroll
    for (int j = 0; j < 4; ++j) acc[i][j] = (f32x4){0.f, 0.f, 0.f, 0.f};

  int aoff[4], boff[4];
#pragma unroll
  for (int f = 0; f < 4; ++f) {
    const int ar = wr * 64 + f * 16 + (lane & 15);
    aoff[f] = ar * 32 + swz(ar, lane >> 4) * 8;
    const int br = wc * 64 + f * 16 + (lane & 15);
    boff[f] = 4096 + br * 32 + swz(br, lane >> 4) * 8;
  }

  s16x8 a0 = *(const s16x8*)(Arow);
  s16x8 a1 = *(const s16x8*)(Arow + 8);
  s16x8 b0 = *(const s16x8*)(Wrow);
  s16x8 b1 = *(const s16x8*)(Wrow + 8);

  for (int k0 = 0; k0 < 512; k0 += 32) {
    __syncthreads();
    *(s16x8*)&lds[asw0] = a0;
    *(s16x8*)&lds[asw1] = a1;
    *(s16x8*)&lds[4096 + asw0] = b0;
    *(s16x8*)&lds[4096 + asw1] = b1;
    __syncthreads();
    if (k0 + 32 < 512) {
      a0 = *(const s16x8*)(Arow + k0 + 32);
      a1 = *(const s16x8*)(Arow + k0 + 40);
      b0 = *(const s16x8*)(Wrow + k0 + 32);
      b1 = *(const s16x8*)(Wrow + k0 + 40);
    }
    s16x8 af[4], bf[4];
#pragma unroll
    for (int f = 0; f < 4; ++f) {
      af[f] = *(const s16x8*)&lds[aoff[f]];
      bf[f] = *(const s16x8*)&lds[boff[f]];
    }
#pragma unroll
    for (int i = 0; i < 4; ++i)
#pragma unroll
      for (int j = 0; j < 4; ++j)
        acc[i][j] = MFMA(af[i], bf[j], acc[i][j], 0, 0, 0);
  }

#pragma unroll
  for (int i = 0; i < 4; ++i) {
    const int rb = m0 + wr * 64 + i * 16 + (lane >> 4) * 4;
#pragma unroll
    for (int g = 0; g < 4; ++g) {
      const int row = rb + g;
      const int b2_ = row >> 11, t2 = row & 2047;
      const int tw = zd ? (2047 - t2) : t2;
      float* crow = Cout + ((size_t)((b2_ << 11) + tw)) * 256 + n0 + wc * 64 + (lane & 15);
#pragma unroll
      for (int j = 0; j < 4; ++j)
        crow[j * 16] = acc[i][j][g];
    }
  }
}

// ---------------------------------------------------------------------------
// causal depthwise conv, strip-mined, dir-batched; OUTPUT = split-bf16 hi/lo
// planes (hi at xch[row*640+c], lo at +XCLO). Same bytes as fp32.
// ---------------------------------------------------------------------------
__global__ __launch_bounds__(256) void k_conv(
    const ushort* __restrict__ xbc,
    const float* __restrict__ Wc0, const float* __restrict__ Wc1,
    const float* __restrict__ bc0, const float* __restrict__ bc1,
    ushort* __restrict__ xch)
{
  const int zd = blockIdx.z;
  xbc += (size_t)zd * XBCB_STR;
  xch += (size_t)zd * XCV_STR;
  const float* Wc = zd ? Wc1 : Wc0;
  const float* bc = zd ? bc1 : bc0;

  const int t = threadIdx.x;
  const int cg = blockIdx.x * 8 + (t & 7);
  const int c0 = cg * 8;
  const int rt0 = (blockIdx.y * 32 + (t >> 3)) * 16;

  float4 wv[8];
  const float4* wp = (const float4*)(Wc + c0 * 4);
#pragma unroll
  for (int e = 0; e < 8; ++e) wv[e] = wp[e];
  float bias[8];
#pragma unroll
  for (int e = 0; e < 8; ++e) bias[e] = bc[c0 + e];

  const s16x8 zz = (s16x8){0, 0, 0, 0, 0, 0, 0, 0};
  s16x8 w0, w1, w2;
  {
    const int l0 = rt0 & 2047;
    w0 = (l0 >= 3) ? *(const s16x8*)(xbc + (size_t)(rt0 - 3) * 640 + c0) : zz;
    w1 = (l0 >= 2) ? *(const s16x8*)(xbc + (size_t)(rt0 - 2) * 640 + c0) : zz;
    w2 = (l0 >= 1) ? *(const s16x8*)(xbc + (size_t)(rt0 - 1) * 640 + c0) : zz;
  }

#pragma unroll 4
  for (int i = 0; i < 16; ++i) {
    const int row = rt0 + i;
    const s16x8 cur = *(const s16x8*)(xbc + (size_t)row * 640 + c0);
    s16x8 hh, ll;
#pragma unroll
    for (int e = 0; e < 8; ++e) {
      const float* w = (const float*)&wv[e];
      float a = bias[e];
      a = fmaf(b2f((ushort)w0[e]), w[0], a);
      a = fmaf(b2f((ushort)w1[e]), w[1], a);
      a = fmaf(b2f((ushort)w2[e]), w[2], a);
      a = fmaf(b2f((ushort)cur[e]), w[3], a);
      const float sv = siluf(a);
      const ushort hb = f2b(sv);
      hh[e] = (short)hb;
      ll[e] = (short)f2b(sv - b2f(hb));
    }
    ushort* op = xch + (size_t)row * 640 + c0;
    *(s16x8*)op = hh;
    *(s16x8*)(op + XCLO) = ll;
    w0 = w1; w1 = w2; w2 = cur;
  }
}

// ---------------------------------------------------------------------------
// Chunked SSD pass 1: staging = pure copies from the hi/lo planes (no cvt).
// P3 reads x = hi+lo from Xt LDS planes; writes ylocal split hi/lo to planes.
// ---------------------------------------------------------------------------
__global__ __launch_bounds__(256) void k_scan1(
    ushort* __restrict__ xch, const float* __restrict__ dt,
    const float* __restrict__ dtA,
    const float* __restrict__ Dp0, const float* __restrict__ Dp1,
    ushort* __restrict__ hin, float* __restrict__ Sbuf,
    float* __restrict__ PT)
{
  const int zd = blockIdx.z;
  xch  += (size_t)zd * XCV_STR;
  dt   += (size_t)zd * DT_STR;
  dtA  += (size_t)zd * DT_STR;
  hin  += (size_t)zd * HINP_STR;
  Sbuf += (size_t)zd * SB_STR;
  PT   += (size_t)zd * PT_STR;
  const float* Dp = zd ? Dp1 : Dp0;

  const int c = blockIdx.x & (NC - 1);
  const int bhi = blockIdx.x >> 5;
  const int b = bhi >> 3, h = bhi & 7;
  const int tid = threadIdx.x;
  const int lane = tid & 63;
  const int wid = tid >> 6;
  const int r0 = b * 2048 + c * TC;
  const int hbase = h * 64;
  __shared__ __align__(16) ushort tiles[24576];
  __shared__ float Ssh[64], dtsh[64], vsh[64];
  enum { PCH = 0, PCL = 4096, PBH = 8192, PBL = 12288, PXH = 16384, PXL = 20480 };

  if (tid < 64) {
    float a = dtA[(size_t)(r0 + tid) * 8 + h];
    const float d = dt[(size_t)(r0 + tid) * 8 + h];
#pragma unroll
    for (int off = 1; off < 64; off <<= 1) {
      const float t = __shfl_up(a, off);
      if (tid >= off) a += t;
    }
    const float slast = __shfl(a, 63);
    Ssh[tid] = a;
    dtsh[tid] = d;
    vsh[tid] = expf(a - slast) * d;
    Sbuf[(size_t)bhi * 2048 + c * TC + tid] = a;
    if (tid == 63) PT[bhi * NC + c] = expf(-slast);
  }
  // P1: copy hi/lo planes -> LDS (no conversion)
  {
    const int r = tid >> 2, c0 = (tid & 3) * 16;
    const ushort* rowh = xch + (size_t)(r0 + r) * 640;
    const ushort* rowl = rowh + XCLO;
    *(s16x8*)&tiles[toff(PBH, r, c0)]     = *(const s16x8*)(rowh + 512 + c0);
    *(s16x8*)&tiles[toff(PBH, r, c0 + 8)] = *(const s16x8*)(rowh + 512 + c0 + 8);
    *(s16x8*)&tiles[toff(PBL, r, c0)]     = *(const s16x8*)(rowl + 512 + c0);
    *(s16x8*)&tiles[toff(PBL, r, c0 + 8)] = *(const s16x8*)(rowl + 512 + c0 + 8);
    *(s16x8*)&tiles[toff(PCH, r, c0)]     = *(const s16x8*)(rowh + 576 + c0);
    *(s16x8*)&tiles[toff(PCH, r, c0 + 8)] = *(const s16x8*)(rowh + 576 + c0 + 8);
    *(s16x8*)&tiles[toff(PCL, r, c0)]     = *(const s16x8*)(rowl + 576 + c0);
    *(s16x8*)&tiles[toff(PCL, r, c0 + 8)] = *(const s16x8*)(rowl + 576 + c0 + 8);
    *(s16x8*)&tiles[toff(PXH, r, c0)]     = *(const s16x8*)(rowh + hbase + c0);
    *(s16x8*)&tiles[toff(PXH, r, c0 + 8)] = *(const s16x8*)(rowh + hbase + c0 + 8);
    *(s16x8*)&tiles[toff(PXL, r, c0)]     = *(const s16x8*)(rowl + hbase + c0);
    *(s16x8*)&tiles[toff(PXL, r, c0 + 8)] = *(const s16x8*)(rowl + hbase + c0 + 8);
  }
  __syncthreads();   // sync1

  const int ib = wid * 16;
  const int frow = lane & 15;
  const int fkc = lane >> 4;

  const int tp = tid >> 2;
  const int tj0 = (tid & 3) * 16;
  s16x8 xtr[4], btr[4];
#pragma unroll
  for (int cc = 0; cc < 2; ++cc) {
    const int j0 = tj0 + cc * 8;
    s16x8 vh, vl, wh, wl;
#pragma unroll
    for (int e = 0; e < 8; ++e) {
      const int ax = toff(PXH, j0 + e, tp);
      vh[e] = (short)tiles[ax];
      vl[e] = (short)tiles[ax + 4096];
      const int ab = toff(PBH, j0 + e, tp);
      wh[e] = (short)tiles[ab];
      wl[e] = (short)tiles[ab + 4096];
    }
    xtr[cc] = vh; xtr[cc + 2] = vl;
    btr[cc] = wh; btr[cc + 2] = wl;
  }

  s16x8 pah[2], pal[2];
#pragma unroll
  for (int ks = 0; ks < 2; ++ks) {
    pah[ks] = *(const s16x8*)&tiles[toff(PCH, ib + frow, ks * 32 + fkc * 8)];
    pal[ks] = *(const s16x8*)&tiles[toff(PCL, ib + frow, ks * 32 + fkc * 8)];
  }
  f32x4 acc[4];
#pragma unroll
  for (int jt = 0; jt < 4; ++jt) acc[jt] = (f32x4){0.f, 0.f, 0.f, 0.f};
#pragma unroll
  for (int jt = 0; jt < 4; ++jt) {
#pragma unroll
    for (int ks = 0; ks < 2; ++ks) {
      const s16x8 tbh = *(const s16x8*)&tiles[toff(PBH, jt * 16 + frow, ks * 32 + fkc * 8)];
      const s16x8 tbl = *(const s16x8*)&tiles[toff(PBL, jt * 16 + frow, ks * 32 + fkc * 8)];
      acc[jt] = MFMA(pah[ks], tbh, acc[jt], 0, 0, 0);
      acc[jt] = MFMA(pah[ks], tbl, acc[jt], 0, 0, 0);
      acc[jt] = MFMA(pal[ks], tbh, acc[jt], 0, 0, 0);
    }
  }
  float Si[4];
#pragma unroll
  for (int g = 0; g < 4; ++g) Si[g] = Ssh[ib + fkc * 4 + g];
#pragma unroll
  for (int jt = 0; jt < 4; ++jt) {
    const int j = jt * 16 + frow;
    const float Sj = Ssh[j], dj = dtsh[j];
#pragma unroll
    for (int g = 0; g < 4; ++g) {
      const int i = ib + fkc * 4 + g;
      const float w = (j <= i) ? __expf(Sj - Si[g]) * dj : 0.f;
      const float gt = acc[jt][g] * w;
      const ushort gh = f2b(gt);
      tiles[toff(PCH, i, j)] = gh;
      tiles[toff(PCL, i, j)] = f2b(gt - b2f(gh));
    }
  }
  __syncthreads();   // sync2

#pragma unroll
  for (int cc = 0; cc < 2; ++cc) {
    *(s16x8*)&tiles[toff(PXH, tp, tj0 + cc * 8)] = xtr[cc];
    *(s16x8*)&tiles[toff(PXL, tp, tj0 + cc * 8)] = xtr[cc + 2];
    *(s16x8*)&tiles[toff(PBH, tp, tj0 + cc * 8)] = btr[cc];
    *(s16x8*)&tiles[toff(PBL, tp, tj0 + cc * 8)] = btr[cc + 2];
  }
  __syncthreads();   // sync3

  s16x8 gah[2], gal[2];
#pragma unroll
  for (int ks = 0; ks < 2; ++ks) {
    gah[ks] = *(const s16x8*)&tiles[toff(PCH, ib + frow, ks * 32 + fkc * 8)];
    gal[ks] = *(const s16x8*)&tiles[toff(PCL, ib + frow, ks * 32 + fkc * 8)];
  }
  const float dpv = Dp[h];
#pragma unroll
  for (int pt = 0; pt < 4; ++pt) {
    f32x4 accY = (f32x4){0.f, 0.f, 0.f, 0.f};
#pragma unroll
    for (int ks = 0; ks < 2; ++ks) {
      const s16x8 xh = *(const s16x8*)&tiles[toff(PXH, pt * 16 + frow, ks * 32 + fkc * 8)];
      const s16x8 xl = *(const s16x8*)&tiles[toff(PXL, pt * 16 + frow, ks * 32 + fkc * 8)];
      accY = MFMA(gah[ks], xh, accY, 0, 0, 0);
      accY = MFMA(gah[ks], xl, accY, 0, 0, 0);
      accY = MFMA(gal[ks], xh, accY, 0, 0, 0);
    }
    const int p = pt * 16 + frow;
#pragma unroll
    for (int g = 0; g < 4; ++g) {
      const int i = ib + fkc * 4 + g;
      const int ax = toff(PXH, p, i);           // Xt[p][i] = x(row i, col p)
      const float xv = b2f(tiles[ax]) + b2f(tiles[ax + 4096]);
      const float y = accY[g] + dpv * xv;
      const ushort hb = f2b(y);
      ushort* gp = xch + (size_t)(r0 + i) * 640 + hbase + p;
      gp[0] = hb;
      gp[XCLO] = f2b(y - b2f(hb));
    }
  }

  s16x8 xvh[2], xvl[2];
#pragma unroll
  for (int ks = 0; ks < 2; ++ks) {
    const int J0 = ks * 32 + fkc * 8;
    const s16x8 xh = *(const s16x8*)&tiles[toff(PXH, ib + frow, J0)];
    const s16x8 xl = *(const s16x8*)&tiles[toff(PXL, ib + frow, J0)];
#pragma unroll
    for (int e = 0; e < 8; ++e) {
      const float xf = (b2f((ushort)xh[e]) + b2f((ushort)xl[e])) * vsh[J0 + e];
      const ushort nh = f2b(xf);
      xvh[ks][e] = (short)nh;
      xvl[ks][e] = (short)f2b(xf - b2f(nh));
    }
  }
  ushort* hbp = hin + (((size_t)(bhi * NC + c)) << 12);
#pragma unroll
  for (int nt = 0; nt < 4; ++nt) {
    f32x4 accC = (f32x4){0.f, 0.f, 0.f, 0.f};
#pragma unroll
    for (int ks = 0; ks < 2; ++ks) {
      const s16x8 tbh = *(const s16x8*)&tiles[toff(PBH, nt * 16 + frow, ks * 32 + fkc * 8)];
      const s16x8 tbl = *(const s16x8*)&tiles[toff(PBL, nt * 16 + frow, ks * 32 + fkc * 8)];
      accC = MFMA(xvh[ks], tbh, accC, 0, 0, 0);
      accC = MFMA(xvh[ks], tbl, accC, 0, 0, 0);
      accC = MFMA(xvl[ks], tbh, accC, 0, 0, 0);
    }
    const int n = nt * 16 + frow;
    const int kss = nt >> 1;
    const int nlo3 = (n >> 3) & 3, ne = n & 7;
#pragma unroll
    for (int g = 0; g < 4; ++g) {
      const int plo = fkc * 4 + g;
      const int off = ((wid * 2 + kss) << 9) + (nlo3 * 16 + plo) * 8 + ne;
      const float v = accC[g];
      const ushort vh = f2b(v);
      hbp[off] = vh;
      hbp[off + HIOFF] = f2b(v - b2f(vh));
    }
  }
}

// Pass 2: cross-chunk state propagation, dir-batched (unchanged).
__global__ __launch_bounds__(256) void k_scan2(
    ushort* __restrict__ hin, const float* __restrict__ PT)
{
  const int zd = blockIdx.z;
  hin += (size_t)zd * HINP_STR;
  PT  += (size_t)zd * PT_STR;
  const int bh = blockIdx.x >> 2, jt = blockIdx.x & 3;
  const int t = threadIdx.x;
  float hv[4] = {0.f, 0.f, 0.f, 0.f};
  for (int c = 0; c < NC; ++c) {
    ushort* base = hin + (((size_t)(bh * NC + c)) << 12) + (jt << 10) + t * 4;
    const float pt = PT[bh * NC + c];
    const ushort4 uh = *(const ushort4*)base;
    const ushort4 ul = *(const ushort4*)(base + HIOFF);
    const float vals[4] = {b2f(uh.x) + b2f(ul.x), b2f(uh.y) + b2f(ul.y),
                           b2f(uh.z) + b2f(ul.z), b2f(uh.w) + b2f(ul.w)};
    ushort4 nh, nl;
    ushort* nhp = (ushort*)&nh; ushort* nlp = (ushort*)&nl;
#pragma unroll
    for (int k = 0; k < 4; ++k) {
      const float old = hv[k];
      hv[k] = fmaf(pt, hv[k], vals[k]);
      const ushort oh = f2b(old);
      nhp[k] = oh;
      nlp[k] = f2b(old - b2f(oh));
    }
    *(ushort4*)base = nh;
    *(ushort4*)(base + HIOFF) = nl;
  }
}

// ---------------------------------------------------------------------------
// Fused pass 3: C stage = copies from hi/lo planes; ylocal = hi+lo.
// ---------------------------------------------------------------------------
__global__ __launch_bounds__(512) void k_scan3f(
    const ushort* __restrict__ xch, const ushort* __restrict__ z,
    const ushort* __restrict__ hin, const float* __restrict__ Sbuf,
    const float* __restrict__ nw0, const float* __restrict__ nw1,
    ushort* __restrict__ ybf)
{
  const int zd = blockIdx.z;
  xch  += (size_t)zd * XCV_STR;
  z    += (size_t)zd * ZB_STR;
  hin  += (size_t)zd * HINP_STR;
  Sbuf += (size_t)zd * SB_STR;
  ybf  += (size_t)zd * ZB_STR;
  const float* normw = zd ? nw1 : nw0;

  const int c = blockIdx.x & (NC - 1);
  const int b = blockIdx.x >> 5;
  const int tid = threadIdx.x;
  const int lane = tid & 63;
  const int h = tid >> 6;
  const int r0 = b * 2048 + c * TC;
  const int frow = lane & 15;
  const int fk = (lane >> 4) * 8;
  __shared__ __align__(16) ushort ybuf[64 * 524];
  __shared__ float Esh[8][64];
  __shared__ float partial[64][9];
  __shared__ float scale[64];

  {
    const int r = tid >> 3, c0 = (tid & 7) * 8;
    const ushort* rowh = xch + (size_t)(r0 + r) * 640 + 576 + c0;
    *(s16x8*)&ybuf[soff(0, r, c0)]    = *(const s16x8*)rowh;
    *(s16x8*)&ybuf[soff(4608, r, c0)] = *(const s16x8*)(rowh + XCLO);
  }
  Esh[h][lane] = expf(-Sbuf[(size_t)((b * 8 + h) << 11) + c * TC + lane]);
  __syncthreads();

  const size_t cbase = ((size_t)((b * 8 + h) * NC + c)) << 12;
  s16x8 Bh[4][2], Bl[4][2];
  const ushort* hb = hin + cbase + lane * 8;
#pragma unroll
  for (int jt = 0; jt < 4; ++jt)
#pragma unroll
    for (int ks = 0; ks < 2; ++ks) {
      Bh[jt][ks] = *(const s16x8*)(hb + ((jt * 2 + ks) << 9));
      Bl[jt][ks] = *(const s16x8*)(hb + ((jt * 2 + ks) << 9) + HIOFF);
    }
  s16x8 Ah[4][2], Al[4][2];
#pragma unroll
  for (int it = 0; it < 4; ++it)
#pragma unroll
    for (int ks = 0; ks < 2; ++ks) {
      Ah[it][ks] = *(const s16x8*)&ybuf[soff(0, it * 16 + frow, ks * 32 + fk)];
      Al[it][ks] = *(const s16x8*)&ybuf[soff(4608, it * 16 + frow, ks * 32 + fk)];
    }

  f32x4 acc[4][4];
#pragma unroll
  for (int it = 0; it < 4; ++it)
#pragma unroll
    for (int jt = 0; jt < 4; ++jt) acc[it][jt] = (f32x4){0.f, 0.f, 0.f, 0.f};
#pragma unroll
  for (int it = 0; it < 4; ++it)
#pragma unroll
    for (int jt = 0; jt < 4; ++jt)
#pragma unroll
      for (int ks = 0; ks < 2; ++ks) {
        acc[it][jt] = MFMA(Ah[it][ks], Bh[jt][ks], acc[it][jt], 0, 0, 0);
        acc[it][jt] = MFMA(Ah[it][ks], Bl[jt][ks], acc[it][jt], 0, 0, 0);
        acc[it][jt] = MFMA(Al[it][ks], Bh[jt][ks], acc[it][jt], 0, 0, 0);
      }

  float rowsq[4][4];
#pragma unroll
  for (int it = 0; it < 4; ++it)
#pragma unroll
    for (int g = 0; g < 4; ++g) rowsq[it][g] = 0.f;
#pragma unroll
  for (int it = 0; it < 4; ++it)
#pragma unroll
    for (int jt = 0; jt < 4; ++jt) {
      const int gcol = h * 64 + jt * 16 + frow;
#pragma unroll
      for (int g = 0; g < 4; ++g) {
        const int row = it * 16 + (lane >> 4) * 4 + g;
        const size_t gi = (size_t)(r0 + row) * 640 + gcol;
        const float yl = b2f(xch[gi]) + b2f(xch[gi + XCLO]);
        const float zf = b2f(z[(size_t)(r0 + row) * 512 + gcol]);
        const float y = (yl + Esh[h][row] * acc[it][jt][g]) * siluf(zf);
        acc[it][jt][g] = y;
        rowsq[it][g] = fmaf(y, y, rowsq[it][g]);
      }
    }
#pragma unroll
  for (int it = 0; it < 4; ++it)
#pragma unroll
    for (int g = 0; g < 4; ++g) {
      float s = rowsq[it][g];
      s += __shfl_xor(s, 1);
      s += __shfl_xor(s, 2);
      s += __shfl_xor(s, 4);
      s += __shfl_xor(s, 8);
      if (frow == 0) partial[it * 16 + (lane >> 4) * 4 + g][h] = s;
    }
  __syncthreads();
  if (tid < 64) {
    float s = 0.f;
#pragma unroll
    for (int hh = 0; hh < 8; ++hh) s += partial[tid][hh];
    scale[tid] = rsqrtf(s * (1.f / 512.f) + 1e-5f);
  }
  __syncthreads();

  float wreg[4];
#pragma unroll
  for (int jt = 0; jt < 4; ++jt) wreg[jt] = normw[h * 64 + jt * 16 + frow];
#pragma unroll
  for (int it = 0; it < 4; ++it)
#pragma unroll
    for (int jt = 0; jt < 4; ++jt) {
      const int col = h * 64 + jt * 16 + frow;
#pragma unroll
      for (int g = 0; g < 4; ++g) {
        const int row = it * 16 + (lane >> 4) * 4 + g;
        ybuf[row * 524 + col] = f2b(acc[it][jt][g] * scale[row] * wreg[jt]);
      }
    }
  __syncthreads();
#pragma unroll
  for (int j = 0; j < 8; ++j) {
    const int flat = j * 4096 + tid * 8;
    const int row = flat >> 9, col = flat & 511;
    const ushort4 u0 = *(const ushort4*)&ybuf[row * 524 + col];
    const ushort4 u1 = *(const ushort4*)&ybuf[row * 524 + col + 4];
    s16x8 o;
    o[0] = (short)u0.x; o[1] = (short)u0.y; o[2] = (short)u0.z; o[3] = (short)u0.w;
    o[4] = (short)u1.x; o[5] = (short)u1.y; o[6] = (short)u1.z; o[7] = (short)u1.w;
    *(s16x8*)(ybf + (size_t)(r0 + row) * 512 + col) = o;
  }
}

__global__ __launch_bounds__(256) void k_hpart(
    const float* __restrict__ hf, const float* __restrict__ hb,
    float* __restrict__ part)
{
  const int g = blockIdx.x;
  const int b = g >> 5, seg = g & 31;
  const int m = threadIdx.x;
  float s = 0.f;
  for (int l = seg * 64; l < seg * 64 + 64; ++l) {
    const size_t idx = ((size_t)b * 2048 + l) * 256 + m;
    s += hf[idx] + hb[idx];
  }
  part[(size_t)g * 256 + m] = s;
}

__global__ __launch_bounds__(256) void k_hfinal(
    const float* __restrict__ part, float* __restrict__ H)
{
  const int b = blockIdx.x;
  const int m = threadIdx.x;
  float s = 0.f;
  for (int g = 0; g < 32; ++g) s += part[(size_t)(b * 32 + g) * 256 + m];
  H[b * 256 + m] = s * (1.f / 2048.f);
}

extern "C" void kernel_launch(void* const* d_in, const int* in_sizes, int n_in,
                              void* d_out, int out_size, void* d_ws, size_t ws_size,
                              hipStream_t stream) {
  const float* x_in = (const float*)d_in[0];
  const float* Win[2]    = {(const float*)d_in[1],  (const float*)d_in[9]};
  const float* Wconv[2]  = {(const float*)d_in[2],  (const float*)d_in[10]};
  const float* bconv[2]  = {(const float*)d_in[3],  (const float*)d_in[11]};
  const float* dtbias[2] = {(const float*)d_in[4],  (const float*)d_in[12]};
  const float* Alog[2]   = {(const float*)d_in[5],  (const float*)d_in[13]};
  const float* Dpar[2]   = {(const float*)d_in[6],  (const float*)d_in[14]};
  const float* normw[2]  = {(const float*)d_in[7],  (const float*)d_in[15]};
  const float* Wout[2]   = {(const float*)d_in[8],  (const float*)d_in[16]};

  float* ws = (float*)d_ws;
  // layout (float offsets); total 61,288,448 floats = 245.2 MB (ws = 256 MiB)
  ushort* zb    = (ushort*)ws;                        // 2 x ZB_STR   [0, 8388608)
  ushort* ybf   = zb;                                 // alias
  ushort* xbcb  = (ushort*)(ws + 8388608);            // 2 x XBCB_STR [8388608, 18874368)
  ushort* hinp  = (ushort*)(ws + 18874368);           // 2 x HINP_STR [18874368, 35651584)
  ushort* xch   = (ushort*)(ws + 35651584);           // 2 x XCV_STR  [35651584, 56623104)
  float* dtb     = ws + 56623104;                     // 2 x DT_STR
  float* dab     = ws + 56885248;                     // 2 x DT_STR
  float* Sbuf    = ws + 57147392;                     // 2 x SB_STR
  float* PT      = ws + 57409536;                     // 2 x PT_STR
  float* part    = ws + 57413632;                     // 65,536
  ushort* xbf    = (ushort*)(ws + 57479168);          // 2,097,152 floats
  ushort* Winb   = (ushort*)(ws + 59576320);          // 1,187,840 floats
  ushort* Woutb  = (ushort*)(ws + 60764160);          // 524,288 floats

  float* hF = (float*)d_out;
  float* hB = hF + (size_t)8 * 2048 * 256;
  float* Hm = hB + (size_t)8 * 2048 * 256;

  // one-time bf16 conversions
  k_cvt<<<580, 256, 0, stream>>>(Win[0], Winb, 148480);
  k_cvt<<<580, 256, 0, stream>>>(Win[1], Winb + 1187840, 148480);
  k_cvt<<<256, 256, 0, stream>>>(Wout[0], Woutb, 65536);
  k_cvt<<<256, 256, 0, stream>>>(Wout[1], Woutb + 524288, 65536);
  k_cvt<<<2048, 256, 0, stream>>>(x_in, xbf, 524288);

  for (int layer = 0; layer < 4; ++layer) {
    const float* Wc0 = Wconv[0] + (size_t)layer * 640 * 4;
    const float* Wc1 = Wconv[1] + (size_t)layer * 640 * 4;
    const float* bc0 = bconv[0] + (size_t)layer * 640;
    const float* bc1 = bconv[1] + (size_t)layer * 640;

    k_gemmb<<<dim3(128, 10, 2), 256, 0, stream>>>(
        xbf, Winb, layer, zb, xbcb,
        dtbias[0] + layer * 8, dtbias[1] + layer * 8,
        Alog[0] + layer * 8, Alog[1] + layer * 8, dtb, dab);
    k_conv<<<dim3(10, 32, 2), 256, 0, stream>>>(xbcb, Wc0, Wc1, bc0, bc1, xch);
    k_scan1<<<dim3(2048, 1, 2), 256, 0, stream>>>(
        xch, dtb, dab, Dpar[0] + layer * 8, Dpar[1] + layer * 8,
        hinp, Sbuf, PT);
    k_scan2<<<dim3(256, 1, 2), 256, 0, stream>>>(hinp, PT);
    k_scan3f<<<dim3(256, 1, 2), 512, 0, stream>>>(
        xch, zb, hinp, Sbuf,
        normw[0] + layer * 512, normw[1] + layer * 512, ybf);
    if (layer < 3) {
      k_gemmo_mid<<<dim3(128, 2), 256, 0, stream>>>(ybf, Woutb, layer, xbf);
    } else {
      k_gemmo_last<<<dim3(128, 2, 2), 256, 0, stream>>>(ybf, Woutb, hF, hB);
    }
  }
  k_hpart<<<256, 256, 0, stream>>>(hF, hB, part);
  k_hfinal<<<8, 256, 0, stream>>>(part, Hm);
}

// Round 12
// 1002.064 us; speedup vs baseline: 1.1266x; 1.1266x over previous
//
#include <hip/hip_runtime.h>
#include <math.h>

// MicroEncoder: 4-layer bidirectional Mamba2.
// B=8, L=2048, D_MODEL=256, D_INNER=512, NHEADS=8, HEADDIM=64, D_STATE=64,
// CONV_DIM=640, D_IN_PROJ=1160.
// Round 12: conv output = PACKED split-bf16, one uint per element
// (lo<<16 | hi) -- same 4 B/elem and identical coalescing as fp32 xc, but the
// fp32->hi/lo conversion happens once in k_conv. scan1/scan3f staging
// de-interleaves with 2 int ops/elem (no cvt chains). Round-11's 2-plane
// layout (2B scalar accesses, 2x over-fetch) is the thing being fixed.

#define TC 64
#define NC 32
#define SPITCH 72
#define HIOFF 8388608    // ushort offset of lo plane within one dir's hinp

// per-dir strides
#define ZB_STR   8388608u    // ushorts (16384x512)
#define XBCB_STR 10485760u   // ushorts (16384x640)
#define HINP_STR 16777216u   // ushorts (hi+lo planes)
#define XCP_STR  10485760u   // uints (packed hi/lo xc per dir)
#define DT_STR   131072u     // floats
#define SB_STR   131072u     // floats
#define PT_STR   2048u       // floats

typedef __attribute__((ext_vector_type(4))) float f32x4;
typedef __attribute__((ext_vector_type(8))) short s16x8;

#define MFMA __builtin_amdgcn_mfma_f32_16x16x32_bf16

__device__ __forceinline__ float siluf(float x) { return x / (1.f + expf(-x)); }

__device__ __forceinline__ ushort f2b(float f) {
  union { float f; uint u; } v; v.f = f;
  return (ushort)((v.u + 0x7FFFu + ((v.u >> 16) & 1u)) >> 16);
}
__device__ __forceinline__ float b2f(ushort u) {
  union { uint u; float f; } v; v.u = ((uint)u) << 16; return v.f;
}
__device__ __forceinline__ int swz(int r, int c) { return c ^ (r & 3) ^ ((r >> 2) & 3); }

__device__ __forceinline__ int soff(int base, int r, int cc) {
  return base + r * SPITCH + ((((cc >> 3) ^ (r & 7) ^ ((r >> 3) & 7)) << 3) | (cc & 7));
}
__device__ __forceinline__ int toff(int base, int r, int cc) {
  return base + r * 64 + ((((cc >> 3) ^ (r & 7)) << 3) | (cc & 7));
}

// pack fp32 -> (lo16<<16 | hi16) split-bf16
__device__ __forceinline__ uint packf(float y) {
  const ushort hb = f2b(y);
  const ushort lb = f2b(y - b2f(hb));
  return (uint)hb | ((uint)lb << 16);
}
__device__ __forceinline__ float unpackf(uint u) {
  return b2f((ushort)(u & 0xffffu)) + b2f((ushort)(u >> 16));
}

// de-interleave 8 packed uints -> hi/lo s16x8
__device__ __forceinline__ void unzip8(const uint4 u0, const uint4 u1, s16x8& hh, s16x8& ll) {
  const uint a[8] = {u0.x, u0.y, u0.z, u0.w, u1.x, u1.y, u1.z, u1.w};
#pragma unroll
  for (int e = 0; e < 8; ++e) {
    hh[e] = (short)(a[e] & 0xffffu);
    ll[e] = (short)(a[e] >> 16);
  }
}

// stage 16 packed cols -> hi/lo bf16 planes at (r, c0..c0+15), toff layout
__device__ __forceinline__ void stage16p(ushort* tiles, const uint* src,
                                         int bh_, int bl_, int r, int c0) {
  const uint4 u0 = *(const uint4*)(src + c0);
  const uint4 u1 = *(const uint4*)(src + c0 + 4);
  const uint4 u2 = *(const uint4*)(src + c0 + 8);
  const uint4 u3 = *(const uint4*)(src + c0 + 12);
  s16x8 h0, l0, h1, l1;
  unzip8(u0, u1, h0, l0);
  unzip8(u2, u3, h1, l1);
  *(s16x8*)&tiles[toff(bh_, r, c0)]     = h0;
  *(s16x8*)&tiles[toff(bl_, r, c0)]     = l0;
  *(s16x8*)&tiles[toff(bh_, r, c0 + 8)] = h1;
  *(s16x8*)&tiles[toff(bl_, r, c0 + 8)] = l1;
}

__global__ __launch_bounds__(256) void k_cvt(
    const float* __restrict__ src, ushort* __restrict__ dst, int n8)
{
  const int i = blockIdx.x * 256 + threadIdx.x;
  if (i >= n8) return;
  const float4 v0 = *(const float4*)(src + (size_t)i * 8);
  const float4 v1 = *(const float4*)(src + (size_t)i * 8 + 4);
  s16x8 h;
#pragma unroll
  for (int e = 0; e < 4; ++e) h[e] = (short)f2b(((const float*)&v0)[e]);
#pragma unroll
  for (int e = 0; e < 4; ++e) h[e + 4] = (short)f2b(((const float*)&v1)[e]);
  *(s16x8*)(dst + (size_t)i * 8) = h;
}

// ---------------------------------------------------------------------------
// in_proj GEMM, direction-batched via blockIdx.z. (unchanged from round 10)
// ---------------------------------------------------------------------------
__global__ __launch_bounds__(256) void k_gemmb(
    const ushort* __restrict__ A, const ushort* __restrict__ Winb, int layer,
    ushort* __restrict__ zb, ushort* __restrict__ xbc,
    const float* __restrict__ db0, const float* __restrict__ db1,
    const float* __restrict__ Al0, const float* __restrict__ Al1,
    float* __restrict__ dtb, float* __restrict__ dab)
{
  const int zd = blockIdx.z;
  const ushort* W = Winb + ((size_t)zd * 4 + layer) * 296960;  // 1160*256
  zb  += (size_t)zd * ZB_STR;
  xbc += (size_t)zd * XBCB_STR;
  dtb += (size_t)zd * DT_STR;
  dab += (size_t)zd * DT_STR;
  const float* dt_bias = zd ? db1 : db0;
  const float* A_log   = zd ? Al1 : Al0;
  const int N = 1160, K = 256;

  __shared__ __align__(16) ushort lds[17408];
  const int tid = threadIdx.x;
  const int lane = tid & 63;
  const int wid = tid >> 6;
  const int wr = wid >> 1, wc = wid & 1;
  const int m0 = blockIdx.x * 128, n0 = blockIdx.y * 128;

  const int tr = tid >> 1;
  const int th = tid & 1;
  const int gm = m0 + tr;
  const int bb = gm >> 11, tt = gm & 2047;
  const int tphys = zd ? (2047 - tt) : tt;
  const ushort* Arow = A + (size_t)((bb << 11) + tphys) * 256 + th * 16;
  const int wn = n0 + tr;
  const ushort* Wrow = (wn < N) ? (W + (size_t)wn * K + th * 16) : nullptr;

  const int asw0 = tr * 32 + swz(tr, th * 2) * 8;
  const int asw1 = tr * 32 + swz(tr, th * 2 + 1) * 8;

  f32x4 acc[4][4];
#pragma unroll
  for (int i = 0; i < 4; ++i)
#pragma unroll
    for (int j = 0; j < 4; ++j) acc[i][j] = (f32x4){0.f, 0.f, 0.f, 0.f};

  int aoff[4], boff[4];
#pragma unroll
  for (int f = 0; f < 4; ++f) {
    const int ar = wr * 64 + f * 16 + (lane & 15);
    aoff[f] = ar * 32 + swz(ar, lane >> 4) * 8;
    const int br = wc * 64 + f * 16 + (lane & 15);
    boff[f] = 4096 + br * 32 + swz(br, lane >> 4) * 8;
  }

  const s16x8 zz = (s16x8){0, 0, 0, 0, 0, 0, 0, 0};
  s16x8 a0 = *(const s16x8*)(Arow);
  s16x8 a1 = *(const s16x8*)(Arow + 8);
  s16x8 b0 = zz, b1 = zz;
  if (Wrow) {
    b0 = *(const s16x8*)(Wrow);
    b1 = *(const s16x8*)(Wrow + 8);
  }

  for (int k0 = 0; k0 < K; k0 += 32) {
    __syncthreads();
    *(s16x8*)&lds[asw0] = a0;
    *(s16x8*)&lds[asw1] = a1;
    *(s16x8*)&lds[4096 + asw0] = b0;
    *(s16x8*)&lds[4096 + asw1] = b1;
    __syncthreads();
    if (k0 + 32 < K) {
      a0 = *(const s16x8*)(Arow + k0 + 32);
      a1 = *(const s16x8*)(Arow + k0 + 40);
      if (Wrow) {
        b0 = *(const s16x8*)(Wrow + k0 + 32);
        b1 = *(const s16x8*)(Wrow + k0 + 40);
      }
    }
    s16x8 af[4], bf[4];
#pragma unroll
    for (int f = 0; f < 4; ++f) {
      af[f] = *(const s16x8*)&lds[aoff[f]];
      bf[f] = *(const s16x8*)&lds[boff[f]];
    }
#pragma unroll
    for (int i = 0; i < 4; ++i)
#pragma unroll
      for (int j = 0; j < 4; ++j)
        acc[i][j] = MFMA(af[i], bf[j], acc[i][j], 0, 0, 0);
  }

  const int by = blockIdx.y;
  if (by == 9) {
    if (wc == 0 && (lane & 15) < 8) {
      const int cl = lane & 15;
      const float bias = dt_bias[cl];
      const float eAl = expf(A_log[cl]);
#pragma unroll
      for (int i = 0; i < 4; ++i) {
        const int r = m0 + wr * 64 + i * 16 + (lane >> 4) * 4;
#pragma unroll
        for (int g = 0; g < 4; ++g) {
          const float v = acc[i][0][g] + bias;
          const float sp = (v > 20.f) ? v : log1pf(expf(v));
          dtb[(size_t)(r + g) * 8 + cl] = sp;
          dab[(size_t)(r + g) * 8 + cl] = sp * eAl;
        }
      }
    }
    return;
  }
  __syncthreads();
#pragma unroll
  for (int i = 0; i < 4; ++i) {
    const int r = wr * 64 + i * 16 + (lane >> 4) * 4;
#pragma unroll
    for (int j = 0; j < 4; ++j) {
      const int ccol = wc * 64 + j * 16 + (lane & 15);
#pragma unroll
      for (int g = 0; g < 4; ++g)
        lds[(r + g) * 136 + ccol] = f2b(acc[i][j][g]);
    }
  }
  __syncthreads();
  const int rr = tid >> 1, hf = tid & 1;
  const int grow = m0 + rr;
  ushort* dst; int stride, colb;
  if (by < 4) { dst = zb;  stride = 512; colb = n0; }
  else        { dst = xbc; stride = 640; colb = n0 - 512; }
  ushort* dp = dst + (size_t)grow * stride + colb + hf * 64;
  const ushort* sp = &lds[rr * 136 + hf * 64];
#pragma unroll
  for (int q = 0; q < 8; ++q)
    *(s16x8*)(dp + q * 8) = *(const s16x8*)(sp + q * 8);
}

// ---------------------------------------------------------------------------
// Fused out_proj for layers 0-2 (unchanged from round 10).
// ---------------------------------------------------------------------------
__global__ __launch_bounds__(256) void k_gemmo_mid(
    const ushort* __restrict__ ybf, const ushort* __restrict__ Woutb, int layer,
    ushort* __restrict__ xbf)
{
  __shared__ __align__(16) ushort lds[8192];
  const int tid = threadIdx.x;
  const int lane = tid & 63;
  const int wid = tid >> 6;
  const int wr = wid >> 1, wc = wid & 1;
  const int m0 = blockIdx.x * 128, n0 = blockIdx.y * 128;

  const int tr = tid >> 1;
  const int th = tid & 1;
  const int gm = m0 + tr;
  const int bb = gm >> 11, tt = gm & 2047;
  const int wn = n0 + tr;

  const int asw0 = tr * 32 + swz(tr, th * 2) * 8;
  const int asw1 = tr * 32 + swz(tr, th * 2 + 1) * 8;

  f32x4 acc[4][4];
#pragma unroll
  for (int i = 0; i < 4; ++i)
#pragma unroll
    for (int j = 0; j < 4; ++j) acc[i][j] = (f32x4){0.f, 0.f, 0.f, 0.f};

  int aoff[4], boff[4];
#pragma unroll
  for (int f = 0; f < 4; ++f) {
    const int ar = wr * 64 + f * 16 + (lane & 15);
    aoff[f] = ar * 32 + swz(ar, lane >> 4) * 8;
    const int br = wc * 64 + f * 16 + (lane & 15);
    boff[f] = 4096 + br * 32 + swz(br, lane >> 4) * 8;
  }

  for (int dir = 0; dir < 2; ++dir) {
    const int tphys = dir ? (2047 - tt) : tt;
    const ushort* Arow = ybf + (size_t)dir * ZB_STR
                       + (size_t)((bb << 11) + tphys) * 512 + th * 16;
    const ushort* Wrow = Woutb + ((size_t)dir * 4 + layer) * 131072
                       + (size_t)wn * 512 + th * 16;
    s16x8 a0 = *(const s16x8*)(Arow);
    s16x8 a1 = *(const s16x8*)(Arow + 8);
    s16x8 b0 = *(const s16x8*)(Wrow);
    s16x8 b1 = *(const s16x8*)(Wrow + 8);
    for (int k0 = 0; k0 < 512; k0 += 32) {
      __syncthreads();
      *(s16x8*)&lds[asw0] = a0;
      *(s16x8*)&lds[asw1] = a1;
      *(s16x8*)&lds[4096 + asw0] = b0;
      *(s16x8*)&lds[4096 + asw1] = b1;
      __syncthreads();
      if (k0 + 32 < 512) {
        a0 = *(const s16x8*)(Arow + k0 + 32);
        a1 = *(const s16x8*)(Arow + k0 + 40);
        b0 = *(const s16x8*)(Wrow + k0 + 32);
        b1 = *(const s16x8*)(Wrow + k0 + 40);
      }
      s16x8 af[4], bf[4];
#pragma unroll
      for (int f = 0; f < 4; ++f) {
        af[f] = *(const s16x8*)&lds[aoff[f]];
        bf[f] = *(const s16x8*)&lds[boff[f]];
      }
#pragma unroll
      for (int i = 0; i < 4; ++i)
#pragma unroll
        for (int j = 0; j < 4; ++j)
          acc[i][j] = MFMA(af[i], bf[j], acc[i][j], 0, 0, 0);
    }
  }

#pragma unroll
  for (int i = 0; i < 4; ++i) {
    const int rb = m0 + wr * 64 + i * 16 + (lane >> 4) * 4;
#pragma unroll
    for (int g = 0; g < 4; ++g) {
      const size_t rbase = (size_t)(rb + g) * 256 + n0 + wc * 64 + (lane & 15);
#pragma unroll
      for (int j = 0; j < 4; ++j)
        xbf[rbase + j * 16] = f2b(acc[i][j][g]);
    }
  }
}

// ---------------------------------------------------------------------------
// Last-layer out_proj (unchanged from round 10).
// ---------------------------------------------------------------------------
__global__ __launch_bounds__(256) void k_gemmo_last(
    const ushort* __restrict__ ybf, const ushort* __restrict__ Woutb,
    float* __restrict__ hF, float* __restrict__ hB)
{
  const int zd = blockIdx.z;
  const ushort* A = ybf + (size_t)zd * ZB_STR;
  const ushort* W = Woutb + ((size_t)zd * 4 + 3) * 131072;
  float* Cout = zd ? hB : hF;

  __shared__ __align__(16) ushort lds[8192];
  const int tid = threadIdx.x;
  const int lane = tid & 63;
  const int wid = tid >> 6;
  const int wr = wid >> 1, wc = wid & 1;
  const int m0 = blockIdx.x * 128, n0 = blockIdx.y * 128;

  const int tr = tid >> 1;
  const int th = tid & 1;
  const int gm = m0 + tr;
  const ushort* Arow = A + (size_t)gm * 512 + th * 16;
  const int wn = n0 + tr;
  const ushort* Wrow = W + (size_t)wn * 512 + th * 16;

  const int asw0 = tr * 32 + swz(tr, th * 2) * 8;
  const int asw1 = tr * 32 + swz(tr, th * 2 + 1) * 8;

  f32x4 acc[4][4];
#pragma unroll
  for (int i = 0; i < 4; ++i)
#pragma unroll
    for (int j = 0; j < 4; ++j) acc[i][j] = (f32x4){0.f, 0.f, 0.f, 0.f};

  int aoff[4], boff[4];
#pragma unroll
  for (int f = 0; f < 4; ++f) {
    const int ar = wr * 64 + f * 16 + (lane & 15);
    aoff[f] = ar * 32 + swz(ar, lane >> 4) * 8;
    const int br = wc * 64 + f * 16 + (lane & 15);
    boff[f] = 4096 + br * 32 + swz(br, lane >> 4) * 8;
  }

  s16x8 a0 = *(const s16x8*)(Arow);
  s16x8 a1 = *(const s16x8*)(Arow + 8);
  s16x8 b0 = *(const s16x8*)(Wrow);
  s16x8 b1 = *(const s16x8*)(Wrow + 8);

  for (int k0 = 0; k0 < 512; k0 += 32) {
    __syncthreads();
    *(s16x8*)&lds[asw0] = a0;
    *(s16x8*)&lds[asw1] = a1;
    *(s16x8*)&lds[4096 + asw0] = b0;
    *(s16x8*)&lds[4096 + asw1] = b1;
    __syncthreads();
    if (k0 + 32 < 512) {
      a0 = *(const s16x8*)(Arow + k0 + 32);
      a1 = *(const s16x8*)(Arow + k0 + 40);
      b0 = *(const s16x8*)(Wrow + k0 + 32);
      b1 = *(const s16x8*)(Wrow + k0 + 40);
    }
    s16x8 af[4], bf[4];
#pragma unroll
    for (int f = 0; f < 4; ++f) {
      af[f] = *(const s16x8*)&lds[aoff[f]];
      bf[f] = *(const s16x8*)&lds[boff[f]];
    }
#pragma unroll
    for (int i = 0; i < 4; ++i)
#pragma unroll
      for (int j = 0; j < 4; ++j)
        acc[i][j] = MFMA(af[i], bf[j], acc[i][j], 0, 0, 0);
  }

#pragma unroll
  for (int i = 0; i < 4; ++i) {
    const int rb = m0 + wr * 64 + i * 16 + (lane >> 4) * 4;
#pragma unroll
    for (int g = 0; g < 4; ++g) {
      const int row = rb + g;
      const int b2_ = row >> 11, t2 = row & 2047;
      const int tw = zd ? (2047 - t2) : t2;
      float* crow = Cout + ((size_t)((b2_ << 11) + tw)) * 256 + n0 + wc * 64 + (lane & 15);
#pragma unroll
      for (int j = 0; j < 4; ++j)
        crow[j * 16] = acc[i][j][g];
    }
  }
}

// ---------------------------------------------------------------------------
// causal depthwise conv, strip-mined, dir-batched; OUTPUT = packed split-bf16
// (one uint per element).
// ---------------------------------------------------------------------------
__global__ __launch_bounds__(256) void k_conv(
    const ushort* __restrict__ xbc,
    const float* __restrict__ Wc0, const float* __restrict__ Wc1,
    const float* __restrict__ bc0, const float* __restrict__ bc1,
    uint* __restrict__ xcp)
{
  const int zd = blockIdx.z;
  xbc += (size_t)zd * XBCB_STR;
  xcp += (size_t)zd * XCP_STR;
  const float* Wc = zd ? Wc1 : Wc0;
  const float* bc = zd ? bc1 : bc0;

  const int t = threadIdx.x;
  const int cg = blockIdx.x * 8 + (t & 7);
  const int c0 = cg * 8;
  const int rt0 = (blockIdx.y * 32 + (t >> 3)) * 16;

  float4 wv[8];
  const float4* wp = (const float4*)(Wc + c0 * 4);
#pragma unroll
  for (int e = 0; e < 8; ++e) wv[e] = wp[e];
  float bias[8];
#pragma unroll
  for (int e = 0; e < 8; ++e) bias[e] = bc[c0 + e];

  const s16x8 zz = (s16x8){0, 0, 0, 0, 0, 0, 0, 0};
  s16x8 w0, w1, w2;
  {
    const int l0 = rt0 & 2047;
    w0 = (l0 >= 3) ? *(const s16x8*)(xbc + (size_t)(rt0 - 3) * 640 + c0) : zz;
    w1 = (l0 >= 2) ? *(const s16x8*)(xbc + (size_t)(rt0 - 2) * 640 + c0) : zz;
    w2 = (l0 >= 1) ? *(const s16x8*)(xbc + (size_t)(rt0 - 1) * 640 + c0) : zz;
  }

#pragma unroll 4
  for (int i = 0; i < 16; ++i) {
    const int row = rt0 + i;
    const s16x8 cur = *(const s16x8*)(xbc + (size_t)row * 640 + c0);
    uint o[8];
#pragma unroll
    for (int e = 0; e < 8; ++e) {
      const float* w = (const float*)&wv[e];
      float a = bias[e];
      a = fmaf(b2f((ushort)w0[e]), w[0], a);
      a = fmaf(b2f((ushort)w1[e]), w[1], a);
      a = fmaf(b2f((ushort)w2[e]), w[2], a);
      a = fmaf(b2f((ushort)cur[e]), w[3], a);
      o[e] = packf(siluf(a));
    }
    uint* op = xcp + (size_t)row * 640 + c0;
    *(uint4*)op = make_uint4(o[0], o[1], o[2], o[3]);
    *(uint4*)(op + 4) = make_uint4(o[4], o[5], o[6], o[7]);
    w0 = w1; w1 = w2; w2 = cur;
  }
}

// ---------------------------------------------------------------------------
// Chunked SSD pass 1: staging = packed loads + register de-interleave.
// P3 reads x = hi+lo from Xt LDS planes; ylocal written packed (4B scatter).
// ---------------------------------------------------------------------------
__global__ __launch_bounds__(256) void k_scan1(
    uint* __restrict__ xcp, const float* __restrict__ dt,
    const float* __restrict__ dtA,
    const float* __restrict__ Dp0, const float* __restrict__ Dp1,
    ushort* __restrict__ hin, float* __restrict__ Sbuf,
    float* __restrict__ PT)
{
  const int zd = blockIdx.z;
  xcp  += (size_t)zd * XCP_STR;
  dt   += (size_t)zd * DT_STR;
  dtA  += (size_t)zd * DT_STR;
  hin  += (size_t)zd * HINP_STR;
  Sbuf += (size_t)zd * SB_STR;
  PT   += (size_t)zd * PT_STR;
  const float* Dp = zd ? Dp1 : Dp0;

  const int c = blockIdx.x & (NC - 1);
  const int bhi = blockIdx.x >> 5;
  const int b = bhi >> 3, h = bhi & 7;
  const int tid = threadIdx.x;
  const int lane = tid & 63;
  const int wid = tid >> 6;
  const int r0 = b * 2048 + c * TC;
  const int hbase = h * 64;
  __shared__ __align__(16) ushort tiles[24576];
  __shared__ float Ssh[64], dtsh[64], vsh[64];
  enum { PCH = 0, PCL = 4096, PBH = 8192, PBL = 12288, PXH = 16384, PXL = 20480 };

  if (tid < 64) {
    float a = dtA[(size_t)(r0 + tid) * 8 + h];
    const float d = dt[(size_t)(r0 + tid) * 8 + h];
#pragma unroll
    for (int off = 1; off < 64; off <<= 1) {
      const float t = __shfl_up(a, off);
      if (tid >= off) a += t;
    }
    const float slast = __shfl(a, 63);
    Ssh[tid] = a;
    dtsh[tid] = d;
    vsh[tid] = expf(a - slast) * d;
    Sbuf[(size_t)bhi * 2048 + c * TC + tid] = a;
    if (tid == 63) PT[bhi * NC + c] = expf(-slast);
  }
  // P1: packed loads + de-interleave into hi/lo LDS planes
  {
    const int r = tid >> 2, c0 = (tid & 3) * 16;
    const uint* rowp = xcp + (size_t)(r0 + r) * 640;
    stage16p(tiles, rowp + 512, PBH, PBL, r, c0);
    stage16p(tiles, rowp + 576, PCH, PCL, r, c0);
    stage16p(tiles, rowp + hbase, PXH, PXL, r, c0);
  }
  __syncthreads();   // sync1

  const int ib = wid * 16;
  const int frow = lane & 15;
  const int fkc = lane >> 4;

  const int tp = tid >> 2;
  const int tj0 = (tid & 3) * 16;
  s16x8 xtr[4], btr[4];
#pragma unroll
  for (int cc = 0; cc < 2; ++cc) {
    const int j0 = tj0 + cc * 8;
    s16x8 vh, vl, wh, wl;
#pragma unroll
    for (int e = 0; e < 8; ++e) {
      const int ax = toff(PXH, j0 + e, tp);
      vh[e] = (short)tiles[ax];
      vl[e] = (short)tiles[ax + 4096];
      const int ab = toff(PBH, j0 + e, tp);
      wh[e] = (short)tiles[ab];
      wl[e] = (short)tiles[ab + 4096];
    }
    xtr[cc] = vh; xtr[cc + 2] = vl;
    btr[cc] = wh; btr[cc + 2] = wl;
  }

  s16x8 pah[2], pal[2];
#pragma unroll
  for (int ks = 0; ks < 2; ++ks) {
    pah[ks] = *(const s16x8*)&tiles[toff(PCH, ib + frow, ks * 32 + fkc * 8)];
    pal[ks] = *(const s16x8*)&tiles[toff(PCL, ib + frow, ks * 32 + fkc * 8)];
  }
  f32x4 acc[4];
#pragma unroll
  for (int jt = 0; jt < 4; ++jt) acc[jt] = (f32x4){0.f, 0.f, 0.f, 0.f};
#pragma unroll
  for (int jt = 0; jt < 4; ++jt) {
#pragma unroll
    for (int ks = 0; ks < 2; ++ks) {
      const s16x8 tbh = *(const s16x8*)&tiles[toff(PBH, jt * 16 + frow, ks * 32 + fkc * 8)];
      const s16x8 tbl = *(const s16x8*)&tiles[toff(PBL, jt * 16 + frow, ks * 32 + fkc * 8)];
      acc[jt] = MFMA(pah[ks], tbh, acc[jt], 0, 0, 0);
      acc[jt] = MFMA(pah[ks], tbl, acc[jt], 0, 0, 0);
      acc[jt] = MFMA(pal[ks], tbh, acc[jt], 0, 0, 0);
    }
  }
  float Si[4];
#pragma unroll
  for (int g = 0; g < 4; ++g) Si[g] = Ssh[ib + fkc * 4 + g];
#pragma unroll
  for (int jt = 0; jt < 4; ++jt) {
    const int j = jt * 16 + frow;
    const float Sj = Ssh[j], dj = dtsh[j];
#pragma unroll
    for (int g = 0; g < 4; ++g) {
      const int i = ib + fkc * 4 + g;
      const float w = (j <= i) ? __expf(Sj - Si[g]) * dj : 0.f;
      const float gt = acc[jt][g] * w;
      const ushort gh = f2b(gt);
      tiles[toff(PCH, i, j)] = gh;
      tiles[toff(PCL, i, j)] = f2b(gt - b2f(gh));
    }
  }
  __syncthreads();   // sync2

#pragma unroll
  for (int cc = 0; cc < 2; ++cc) {
    *(s16x8*)&tiles[toff(PXH, tp, tj0 + cc * 8)] = xtr[cc];
    *(s16x8*)&tiles[toff(PXL, tp, tj0 + cc * 8)] = xtr[cc + 2];
    *(s16x8*)&tiles[toff(PBH, tp, tj0 + cc * 8)] = btr[cc];
    *(s16x8*)&tiles[toff(PBL, tp, tj0 + cc * 8)] = btr[cc + 2];
  }
  __syncthreads();   // sync3

  s16x8 gah[2], gal[2];
#pragma unroll
  for (int ks = 0; ks < 2; ++ks) {
    gah[ks] = *(const s16x8*)&tiles[toff(PCH, ib + frow, ks * 32 + fkc * 8)];
    gal[ks] = *(const s16x8*)&tiles[toff(PCL, ib + frow, ks * 32 + fkc * 8)];
  }
  const float dpv = Dp[h];
#pragma unroll
  for (int pt = 0; pt < 4; ++pt) {
    f32x4 accY = (f32x4){0.f, 0.f, 0.f, 0.f};
#pragma unroll
    for (int ks = 0; ks < 2; ++ks) {
      const s16x8 xh = *(const s16x8*)&tiles[toff(PXH, pt * 16 + frow, ks * 32 + fkc * 8)];
      const s16x8 xl = *(const s16x8*)&tiles[toff(PXL, pt * 16 + frow, ks * 32 + fkc * 8)];
      accY = MFMA(gah[ks], xh, accY, 0, 0, 0);
      accY = MFMA(gah[ks], xl, accY, 0, 0, 0);
      accY = MFMA(gal[ks], xh, accY, 0, 0, 0);
    }
    const int p = pt * 16 + frow;
#pragma unroll
    for (int g = 0; g < 4; ++g) {
      const int i = ib + fkc * 4 + g;
      const int ax = toff(PXH, p, i);           // Xt[p][i] = x(row i, col p)
      const float xv = b2f(tiles[ax]) + b2f(tiles[ax + 4096]);
      xcp[(size_t)(r0 + i) * 640 + hbase + p] = packf(accY[g] + dpv * xv);
    }
  }

  s16x8 xvh[2], xvl[2];
#pragma unroll
  for (int ks = 0; ks < 2; ++ks) {
    const int J0 = ks * 32 + fkc * 8;
    const s16x8 xh = *(const s16x8*)&tiles[toff(PXH, ib + frow, J0)];
    const s16x8 xl = *(const s16x8*)&tiles[toff(PXL, ib + frow, J0)];
#pragma unroll
    for (int e = 0; e < 8; ++e) {
      const float xf = (b2f((ushort)xh[e]) + b2f((ushort)xl[e])) * vsh[J0 + e];
      const ushort nh = f2b(xf);
      xvh[ks][e] = (short)nh;
      xvl[ks][e] = (short)f2b(xf - b2f(nh));
    }
  }
  ushort* hbp = hin + (((size_t)(bhi * NC + c)) << 12);
#pragma unroll
  for (int nt = 0; nt < 4; ++nt) {
    f32x4 accC = (f32x4){0.f, 0.f, 0.f, 0.f};
#pragma unroll
    for (int ks = 0; ks < 2; ++ks) {
      const s16x8 tbh = *(const s16x8*)&tiles[toff(PBH, nt * 16 + frow, ks * 32 + fkc * 8)];
      const s16x8 tbl = *(const s16x8*)&tiles[toff(PBL, nt * 16 + frow, ks * 32 + fkc * 8)];
      accC = MFMA(xvh[ks], tbh, accC, 0, 0, 0);
      accC = MFMA(xvh[ks], tbl, accC, 0, 0, 0);
      accC = MFMA(xvl[ks], tbh, accC, 0, 0, 0);
    }
    const int n = nt * 16 + frow;
    const int kss = nt >> 1;
    const int nlo3 = (n >> 3) & 3, ne = n & 7;
#pragma unroll
    for (int g = 0; g < 4; ++g) {
      const int plo = fkc * 4 + g;
      const int off = ((wid * 2 + kss) << 9) + (nlo3 * 16 + plo) * 8 + ne;
      const float v = accC[g];
      const ushort vh = f2b(v);
      hbp[off] = vh;
      hbp[off + HIOFF] = f2b(v - b2f(vh));
    }
  }
}

// Pass 2: cross-chunk state propagation, dir-batched (unchanged).
__global__ __launch_bounds__(256) void k_scan2(
    ushort* __restrict__ hin, const float* __restrict__ PT)
{
  const int zd = blockIdx.z;
  hin += (size_t)zd * HINP_STR;
  PT  += (size_t)zd * PT_STR;
  const int bh = blockIdx.x >> 2, jt = blockIdx.x & 3;
  const int t = threadIdx.x;
  float hv[4] = {0.f, 0.f, 0.f, 0.f};
  for (int c = 0; c < NC; ++c) {
    ushort* base = hin + (((size_t)(bh * NC + c)) << 12) + (jt << 10) + t * 4;
    const float pt = PT[bh * NC + c];
    const ushort4 uh = *(const ushort4*)base;
    const ushort4 ul = *(const ushort4*)(base + HIOFF);
    const float vals[4] = {b2f(uh.x) + b2f(ul.x), b2f(uh.y) + b2f(ul.y),
                           b2f(uh.z) + b2f(ul.z), b2f(uh.w) + b2f(ul.w)};
    ushort4 nh, nl;
    ushort* nhp = (ushort*)&nh; ushort* nlp = (ushort*)&nl;
#pragma unroll
    for (int k = 0; k < 4; ++k) {
      const float old = hv[k];
      hv[k] = fmaf(pt, hv[k], vals[k]);
      const ushort oh = f2b(old);
      nhp[k] = oh;
      nlp[k] = f2b(old - b2f(oh));
    }
    *(ushort4*)base = nh;
    *(ushort4*)(base + HIOFF) = nl;
  }
}

// ---------------------------------------------------------------------------
// Fused pass 3: C stage = packed loads + de-interleave; ylocal = unpack(4B).
// ---------------------------------------------------------------------------
__global__ __launch_bounds__(512) void k_scan3f(
    const uint* __restrict__ xcp, const ushort* __restrict__ z,
    const ushort* __restrict__ hin, const float* __restrict__ Sbuf,
    const float* __restrict__ nw0, const float* __restrict__ nw1,
    ushort* __restrict__ ybf)
{
  const int zd = blockIdx.z;
  xcp  += (size_t)zd * XCP_STR;
  z    += (size_t)zd * ZB_STR;
  hin  += (size_t)zd * HINP_STR;
  Sbuf += (size_t)zd * SB_STR;
  ybf  += (size_t)zd * ZB_STR;
  const float* normw = zd ? nw1 : nw0;

  const int c = blockIdx.x & (NC - 1);
  const int b = blockIdx.x >> 5;
  const int tid = threadIdx.x;
  const int lane = tid & 63;
  const int h = tid >> 6;
  const int r0 = b * 2048 + c * TC;
  const int frow = lane & 15;
  const int fk = (lane >> 4) * 8;
  __shared__ __align__(16) ushort ybuf[64 * 524];
  __shared__ float Esh[8][64];
  __shared__ float partial[64][9];
  __shared__ float scale[64];

  {
    const int r = tid >> 3, c0 = (tid & 7) * 8;
    const uint* rowp = xcp + (size_t)(r0 + r) * 640 + 576 + c0;
    const uint4 u0 = *(const uint4*)rowp;
    const uint4 u1 = *(const uint4*)(rowp + 4);
    s16x8 hh, ll;
    unzip8(u0, u1, hh, ll);
    *(s16x8*)&ybuf[soff(0, r, c0)]    = hh;
    *(s16x8*)&ybuf[soff(4608, r, c0)] = ll;
  }
  Esh[h][lane] = expf(-Sbuf[(size_t)((b * 8 + h) << 11) + c * TC + lane]);
  __syncthreads();

  const size_t cbase = ((size_t)((b * 8 + h) * NC + c)) << 12;
  s16x8 Bh[4][2], Bl[4][2];
  const ushort* hb = hin + cbase + lane * 8;
#pragma unroll
  for (int jt = 0; jt < 4; ++jt)
#pragma unroll
    for (int ks = 0; ks < 2; ++ks) {
      Bh[jt][ks] = *(const s16x8*)(hb + ((jt * 2 + ks) << 9));
      Bl[jt][ks] = *(const s16x8*)(hb + ((jt * 2 + ks) << 9) + HIOFF);
    }
  s16x8 Ah[4][2], Al[4][2];
#pragma unroll
  for (int it = 0; it < 4; ++it)
#pragma unroll
    for (int ks = 0; ks < 2; ++ks) {
      Ah[it][ks] = *(const s16x8*)&ybuf[soff(0, it * 16 + frow, ks * 32 + fk)];
      Al[it][ks] = *(const s16x8*)&ybuf[soff(4608, it * 16 + frow, ks * 32 + fk)];
    }

  f32x4 acc[4][4];
#pragma unroll
  for (int it = 0; it < 4; ++it)
#pragma unroll
    for (int jt = 0; jt < 4; ++jt) acc[it][jt] = (f32x4){0.f, 0.f, 0.f, 0.f};
#pragma unroll
  for (int it = 0; it < 4; ++it)
#pragma unroll
    for (int jt = 0; jt < 4; ++jt)
#pragma unroll
      for (int ks = 0; ks < 2; ++ks) {
        acc[it][jt] = MFMA(Ah[it][ks], Bh[jt][ks], acc[it][jt], 0, 0, 0);
        acc[it][jt] = MFMA(Ah[it][ks], Bl[jt][ks], acc[it][jt], 0, 0, 0);
        acc[it][jt] = MFMA(Al[it][ks], Bh[jt][ks], acc[it][jt], 0, 0, 0);
      }

  float rowsq[4][4];
#pragma unroll
  for (int it = 0; it < 4; ++it)
#pragma unroll
    for (int g = 0; g < 4; ++g) rowsq[it][g] = 0.f;
#pragma unroll
  for (int it = 0; it < 4; ++it)
#pragma unroll
    for (int jt = 0; jt < 4; ++jt) {
      const int gcol = h * 64 + jt * 16 + frow;
#pragma unroll
      for (int g = 0; g < 4; ++g) {
        const int row = it * 16 + (lane >> 4) * 4 + g;
        const float yl = unpackf(xcp[(size_t)(r0 + row) * 640 + gcol]);
        const float zf = b2f(z[(size_t)(r0 + row) * 512 + gcol]);
        const float y = (yl + Esh[h][row] * acc[it][jt][g]) * siluf(zf);
        acc[it][jt][g] = y;
        rowsq[it][g] = fmaf(y, y, rowsq[it][g]);
      }
    }
#pragma unroll
  for (int it = 0; it < 4; ++it)
#pragma unroll
    for (int g = 0; g < 4; ++g) {
      float s = rowsq[it][g];
      s += __shfl_xor(s, 1);
      s += __shfl_xor(s, 2);
      s += __shfl_xor(s, 4);
      s += __shfl_xor(s, 8);
      if (frow == 0) partial[it * 16 + (lane >> 4) * 4 + g][h] = s;
    }
  __syncthreads();
  if (tid < 64) {
    float s = 0.f;
#pragma unroll
    for (int hh = 0; hh < 8; ++hh) s += partial[tid][hh];
    scale[tid] = rsqrtf(s * (1.f / 512.f) + 1e-5f);
  }
  __syncthreads();

  float wreg[4];
#pragma unroll
  for (int jt = 0; jt < 4; ++jt) wreg[jt] = normw[h * 64 + jt * 16 + frow];
#pragma unroll
  for (int it = 0; it < 4; ++it)
#pragma unroll
    for (int jt = 0; jt < 4; ++jt) {
      const int col = h * 64 + jt * 16 + frow;
#pragma unroll
      for (int g = 0; g < 4; ++g) {
        const int row = it * 16 + (lane >> 4) * 4 + g;
        ybuf[row * 524 + col] = f2b(acc[it][jt][g] * scale[row] * wreg[jt]);
      }
    }
  __syncthreads();
#pragma unroll
  for (int j = 0; j < 8; ++j) {
    const int flat = j * 4096 + tid * 8;
    const int row = flat >> 9, col = flat & 511;
    const ushort4 u0 = *(const ushort4*)&ybuf[row * 524 + col];
    const ushort4 u1 = *(const ushort4*)&ybuf[row * 524 + col + 4];
    s16x8 o;
    o[0] = (short)u0.x; o[1] = (short)u0.y; o[2] = (short)u0.z; o[3] = (short)u0.w;
    o[4] = (short)u1.x; o[5] = (short)u1.y; o[6] = (short)u1.z; o[7] = (short)u1.w;
    *(s16x8*)(ybf + (size_t)(r0 + row) * 512 + col) = o;
  }
}

__global__ __launch_bounds__(256) void k_hpart(
    const float* __restrict__ hf, const float* __restrict__ hb,
    float* __restrict__ part)
{
  const int g = blockIdx.x;
  const int b = g >> 5, seg = g & 31;
  const int m = threadIdx.x;
  float s = 0.f;
  for (int l = seg * 64; l < seg * 64 + 64; ++l) {
    const size_t idx = ((size_t)b * 2048 + l) * 256 + m;
    s += hf[idx] + hb[idx];
  }
  part[(size_t)g * 256 + m] = s;
}

__global__ __launch_bounds__(256) void k_hfinal(
    const float* __restrict__ part, float* __restrict__ H)
{
  const int b = blockIdx.x;
  const int m = threadIdx.x;
  float s = 0.f;
  for (int g = 0; g < 32; ++g) s += part[(size_t)(b * 32 + g) * 256 + m];
  H[b * 256 + m] = s * (1.f / 2048.f);
}

extern "C" void kernel_launch(void* const* d_in, const int* in_sizes, int n_in,
                              void* d_out, int out_size, void* d_ws, size_t ws_size,
                              hipStream_t stream) {
  const float* x_in = (const float*)d_in[0];
  const float* Win[2]    = {(const float*)d_in[1],  (const float*)d_in[9]};
  const float* Wconv[2]  = {(const float*)d_in[2],  (const float*)d_in[10]};
  const float* bconv[2]  = {(const float*)d_in[3],  (const float*)d_in[11]};
  const float* dtbias[2] = {(const float*)d_in[4],  (const float*)d_in[12]};
  const float* Alog[2]   = {(const float*)d_in[5],  (const float*)d_in[13]};
  const float* Dpar[2]   = {(const float*)d_in[6],  (const float*)d_in[14]};
  const float* normw[2]  = {(const float*)d_in[7],  (const float*)d_in[15]};
  const float* Wout[2]   = {(const float*)d_in[8],  (const float*)d_in[16]};

  float* ws = (float*)d_ws;
  // layout (float offsets); total 61,288,448 floats = 245.2 MB (ws = 256 MiB)
  ushort* zb    = (ushort*)ws;                        // 2 x ZB_STR   [0, 8388608)
  ushort* ybf   = zb;                                 // alias
  ushort* xbcb  = (ushort*)(ws + 8388608);            // 2 x XBCB_STR [8388608, 18874368)
  ushort* hinp  = (ushort*)(ws + 18874368);           // 2 x HINP_STR [18874368, 35651584)
  uint* xcp     = (uint*)(ws + 35651584);             // 2 x XCP_STR  [35651584, 56623104)
  float* dtb     = ws + 56623104;                     // 2 x DT_STR
  float* dab     = ws + 56885248;                     // 2 x DT_STR
  float* Sbuf    = ws + 57147392;                     // 2 x SB_STR
  float* PT      = ws + 57409536;                     // 2 x PT_STR
  float* part    = ws + 57413632;                     // 65,536
  ushort* xbf    = (ushort*)(ws + 57479168);          // 2,097,152 floats
  ushort* Winb   = (ushort*)(ws + 59576320);          // 1,187,840 floats
  ushort* Woutb  = (ushort*)(ws + 60764160);          // 524,288 floats

  float* hF = (float*)d_out;
  float* hB = hF + (size_t)8 * 2048 * 256;
  float* Hm = hB + (size_t)8 * 2048 * 256;

  // one-time bf16 conversions
  k_cvt<<<580, 256, 0, stream>>>(Win[0], Winb, 148480);
  k_cvt<<<580, 256, 0, stream>>>(Win[1], Winb + 1187840, 148480);
  k_cvt<<<256, 256, 0, stream>>>(Wout[0], Woutb, 65536);
  k_cvt<<<256, 256, 0, stream>>>(Wout[1], Woutb + 524288, 65536);
  k_cvt<<<2048, 256, 0, stream>>>(x_in, xbf, 524288);

  for (int layer = 0; layer < 4; ++layer) {
    const float* Wc0 = Wconv[0] + (size_t)layer * 640 * 4;
    const float* Wc1 = Wconv[1] + (size_t)layer * 640 * 4;
    const float* bc0 = bconv[0] + (size_t)layer * 640;
    const float* bc1 = bconv[1] + (size_t)layer * 640;

    k_gemmb<<<dim3(128, 10, 2), 256, 0, stream>>>(
        xbf, Winb, layer, zb, xbcb,
        dtbias[0] + layer * 8, dtbias[1] + layer * 8,
        Alog[0] + layer * 8, Alog[1] + layer * 8, dtb, dab);
    k_conv<<<dim3(10, 32, 2), 256, 0, stream>>>(xbcb, Wc0, Wc1, bc0, bc1, xcp);
    k_scan1<<<dim3(2048, 1, 2), 256, 0, stream>>>(
        xcp, dtb, dab, Dpar[0] + layer * 8, Dpar[1] + layer * 8,
        hinp, Sbuf, PT);
    k_scan2<<<dim3(256, 1, 2), 256, 0, stream>>>(hinp, PT);
    k_scan3f<<<dim3(256, 1, 2), 512, 0, stream>>>(
        xcp, zb, hinp, Sbuf,
        normw[0] + layer * 512, normw[1] + layer * 512, ybf);
    if (layer < 3) {
      k_gemmo_mid<<<dim3(128, 2), 256, 0, stream>>>(ybf, Woutb, layer, xbf);
    } else {
      k_gemmo_last<<<dim3(128, 2, 2), 256, 0, stream>>>(ybf, Woutb, hF, hB);
    }
  }
  k_hpart<<<256, 256, 0, stream>>>(hF, hB, part);
  k_hfinal<<<8, 256, 0, stream>>>(part, Hm);
}